// Round 13
// baseline (355.258 us; speedup 1.0000x reference)
//
#include <hip/hip_runtime.h>
#include <math.h>

#define BATCH 16
#define NN 25200
#define NCLS 80
#define K_PRE 1024
#define MAX_DET 300
#define CONF_T 0.4f
#define IOU_T 0.45f
#define TBIAS 0x3E000000u
// key layout (47 bits): t(25) << 22 | (NN-1-n)(15) << 7 | cls(7)
// (t, n) is unique, so cls in the low bits never affects sort order.
#define RROWS 128
#define OUT_STRIDE 26700  // floats per batch in out (300*89)
// scratch carved from each batch's own out region (written only at the end):
#define SCR_KEYS_OFF 0        // 2048 * 8 B bucket-grouped contender keys
#define SCR_S_OFF    16384    // 1024 * 4 B suffix-scanned hist S
#define SCR_BC_OFF   20480    // 1024 * 4 B per-bucket scatter counters

// ---------------------------------------------------------------------------
// K1: direct-from-global score + argmax -> 64-bit key, PLUS global-atomic
// digit histogram (restored from the proven baseline design; ~1 atomic per
// valid row amortized over 3150 blocks). Last-tile blocks also zero the
// per-batch scatter counters living in the out-scratch region.
// No LDS, no barriers, no per-thread arrays (VGPR-lean, no scratch spill).
// ---------------------------------------------------------------------------
__global__ void __launch_bounds__(512) score_kernel(
    const float* __restrict__ pred, unsigned long long* __restrict__ keys,
    unsigned* __restrict__ ghist, float* __restrict__ out) {
    const int tid = threadIdx.x;
    const int r = tid >> 2, sub = tid & 3;
    const int n = blockIdx.x * RROWS + r;
    const int b = blockIdx.y;

    if (blockIdx.x == 196) {  // zero gsBC for batch b (runs before K2)
        unsigned* bc = (unsigned*)((char*)(out + (size_t)b * OUT_STRIDE) +
                                   SCR_BC_OFF);
        bc[tid] = 0u;
        bc[tid + 512] = 0u;
    }

    float best = 0.0f;
    int bc_i = sub * 20;
    float obj = 0.0f;
    if (n < NN) {
        const float* row = pred + ((size_t)b * NN + n) * 85;
        obj = row[4];
        if (obj > CONF_T) {
            const float* cp = row + 5 + sub * 20;
#pragma unroll
            for (int i = 0; i < 5; ++i) {
                float4 v4 = *reinterpret_cast<const float4*>(cp + 4 * i);
                float v;
                v = v4.x * obj;
                if (v > best) { best = v; bc_i = sub * 20 + 4 * i + 0; }
                v = v4.y * obj;
                if (v > best) { best = v; bc_i = sub * 20 + 4 * i + 1; }
                v = v4.z * obj;
                if (v > best) { best = v; bc_i = sub * 20 + 4 * i + 2; }
                v = v4.w * obj;
                if (v > best) { best = v; bc_i = sub * 20 + 4 * i + 3; }
            }
        }
    }
    // reduce (best, bc) across the 4 lanes of this row, first-max semantics
#pragma unroll
    for (int d = 1; d < 4; d <<= 1) {
        float ov = __shfl_xor(best, d);
        int oc = __shfl_xor(bc_i, d);
        if (ov > best || (ov == best && oc < bc_i)) { best = ov; bc_i = oc; }
    }
    if (n < NN && sub == 0) {
        unsigned t = (obj > CONF_T && best > CONF_T)
                         ? (__float_as_uint(best) - TBIAS) : 0u;
        keys[(size_t)b * NN + n] =
            ((unsigned long long)t << 22) |
            ((unsigned long long)(unsigned)(NN - 1 - n) << 7) |
            (unsigned)bc_i;
        if (t) atomicAdd(&ghist[b * 1024 + (t >> 15)], 1u);
    }
}

// ---------------------------------------------------------------------------
// K2: wide select. 25 blocks per batch; each block scans ghist (LDS suffix
// scan), takes its 1024 keys (ONE load/thread — no spill), and scatters
// contenders (gt(d) < 1024) bucket-grouped into the out-scratch gskeys via
// global atomic counters. Bucket tiling [S[d+1], S[d]) makes written slots
// [0, M) contiguous. Block 0 persists S for K3.
// ---------------------------------------------------------------------------
__global__ void __launch_bounds__(1024) select_kernel(
    const unsigned long long* __restrict__ keys,
    const unsigned* __restrict__ ghist, float* __restrict__ out) {
    __shared__ unsigned sA[1024], sB[1024];
    const int c = blockIdx.x, b = blockIdx.y, tid = threadIdx.x;
    char* scratch = (char*)(out + (size_t)b * OUT_STRIDE);
    unsigned long long* gsk = (unsigned long long*)(scratch + SCR_KEYS_OFF);
    unsigned* gS = (unsigned*)(scratch + SCR_S_OFF);
    unsigned* gBC = (unsigned*)(scratch + SCR_BC_OFF);

    sA[tid] = ghist[b * 1024 + tid];
    __syncthreads();
    unsigned* src = sA;
    unsigned* dst = sB;
    for (int off = 1; off < 1024; off <<= 1) {
        dst[tid] = src[tid] + ((tid + off < 1024) ? src[tid + off] : 0u);
        __syncthreads();
        unsigned* t2 = src; src = dst; dst = t2;
    }
    // src = S (suffix-inclusive). Persist once per batch.
    if (c == 0) gS[tid] = src[tid];

    int i = c * 1024 + tid;
    if (i < NN) {
        unsigned long long key = keys[(size_t)b * NN + i];
        unsigned t = (unsigned)(key >> 22);
        if (t) {
            unsigned d = t >> 15;
            unsigned base = (d < 1023u) ? src[d + 1] : 0u;  // gt(d)
            if (base < 1024u) {
                unsigned pos = base + atomicAdd(&gBC[d], 1u);
                if (pos < 2048u) gsk[pos] = key;
            }
        }
    }
}

// ---------------------------------------------------------------------------
// K3: per batch — load S + contiguous contender keys from out-scratch,
// exact intra-bucket rank -> LDS SoA, wave-per-class bitmask NMS, rank
// scan, output write (overwrites the scratch AFTER all reads) + tail zero.
// All logic identical to the verified fused v2 paths.
// ---------------------------------------------------------------------------
__global__ void __launch_bounds__(1024) nms_out_kernel(
    const float* __restrict__ pred, const float* __restrict__ conf_logits,
    const float* __restrict__ logits, const float* __restrict__ head,
    float* __restrict__ out) {
    __shared__ unsigned sS[1024];
    __shared__ unsigned sA[1024], sB[1024];
    __shared__ unsigned long long skeys[2048];
    __shared__ float bx0[K_PRE], by0[K_PRE], bx1[K_PRE], by1[K_PRE],
        bar_[K_PRE], bsc[K_PRE];
    __shared__ unsigned char bcls[K_PRE];
    __shared__ unsigned short bgi[K_PRE];
    __shared__ unsigned char bkeep[K_PRE];
    __shared__ unsigned sel_dmin;

    const int b = blockIdx.x, tid = threadIdx.x;
    char* scratch = (char*)(out + (size_t)b * OUT_STRIDE);
    const unsigned long long* gsk =
        (const unsigned long long*)(scratch + SCR_KEYS_OFF);
    const unsigned* gS = (const unsigned*)(scratch + SCR_S_OFF);

    sS[tid] = gS[tid];
    if (tid == 0) sel_dmin = 0u;
    __syncthreads();
    // dmin = smallest d with gt(d) < 1024 (unique writer: S monotone)
    {
        unsigned base_d = (tid < 1023) ? sS[tid + 1] : 0u;
        if (base_d < 1024u && (tid == 0 || sS[tid] >= 1024u))
            sel_dmin = (unsigned)tid;
    }
    __syncthreads();
    const unsigned M = sS[sel_dmin];
    const unsigned Mc = M < 2048u ? M : 2048u;

    // contender keys -> LDS (slots [0, Mc) are contiguous-written)
#pragma unroll
    for (int half = 0; half < 2; ++half) {
        int i = tid + (half << 10);
        skeys[i] = ((unsigned)i < Mc) ? gsk[i] : 0ull;
    }
    bcls[tid] = 255;
    bsc[tid] = 0.0f;
    bkeep[tid] = 0;
    __syncthreads();

    // exact rank within bucket; write SoA directly at slot=rank
#pragma unroll
    for (int half = 0; half < 2; ++half) {
        int i = tid + (half << 10);
        unsigned long long key = skeys[i];
        if (key) {
            unsigned t = (unsigned)(key >> 22);
            unsigned d = t >> 15;
            unsigned seg = (d < 1023u) ? sS[d + 1] : 0u;
            unsigned end = sS[d];
            if (end > 2048u) end = 2048u;
            unsigned r = seg;
            for (unsigned j = seg; j < end; ++j)
                if (skeys[j] > key) ++r;
            if (r < 1024u) {
                int n = NN - 1 - (int)((key >> 7) & 32767u);
                const float* row = pred + ((size_t)b * NN + n) * 85;
                float x = row[0], y = row[1], w = row[2], h = row[3];
                float vx0 = x - w * 0.5f, vy0 = y - h * 0.5f;
                float vx1 = x + w * 0.5f, vy1 = y + h * 0.5f;
                bx0[r] = vx0; by0[r] = vy0; bx1[r] = vx1; by1[r] = vy1;
                bar_[r] = (vx1 - vx0) * (vy1 - vy0);
                bsc[r] = __uint_as_float(t + TBIAS);  // bit-exact top_s
                bcls[r] = (unsigned char)(key & 127u);
                bgi[r] = (unsigned short)n;
            }
        }
    }
    __syncthreads();

    // NMS: wave w handles classes {w, w+16, ...}; register-bitmask greedy.
    {
        const int lane = tid & 63;
        const int wv = tid >> 6;
        unsigned char myc[16];
#pragma unroll
        for (int k = 0; k < 16; ++k) myc[k] = bcls[(k << 6) | lane];

        for (int ci = 0; ci < 5; ++ci) {
            const int c = wv + (ci << 4);
            unsigned alive = 0u;
#pragma unroll
            for (int k = 0; k < 16; ++k)
                if (myc[k] == (unsigned char)c) alive |= (1u << k);
            unsigned keptm = 0u;
            for (;;) {
                int s = alive ? ((__builtin_ctz(alive) << 6) | lane)
                              : (1 << 30);
#pragma unroll
                for (int d = 32; d; d >>= 1) {
                    int o = __shfl_xor(s, d);
                    s = o < s ? o : s;
                }
                if (s >= (1 << 30)) break;
                if ((s & 63) == lane) {
                    alive &= ~(1u << (s >> 6));
                    keptm |= (1u << (s >> 6));
                }
                float ax0 = bx0[s], ay0 = by0[s], ax1 = bx1[s], ay1 = by1[s];
                float aa = bar_[s];
                unsigned rem = alive;
                while (rem) {
                    int k = __builtin_ctz(rem);
                    rem &= rem - 1;
                    int j = (k << 6) | lane;
                    float lx = fmaxf(ax0, bx0[j]);
                    float ly = fmaxf(ay0, by0[j]);
                    float rx = fminf(ax1, bx1[j]);
                    float ry = fminf(ay1, by1[j]);
                    float iw = fmaxf(rx - lx, 0.0f);
                    float ih = fmaxf(ry - ly, 0.0f);
                    float inter = iw * ih;
                    float iou = inter / (aa + bar_[j] - inter + 1e-7f);
                    if (iou > IOU_T) alive &= ~(1u << k);
                }
            }
            while (keptm) {
                int k = __builtin_ctz(keptm);
                keptm &= keptm - 1;
                bkeep[(k << 6) | lane] = 1;
            }
        }
    }
    __syncthreads();

    // rank kept rows (inclusive prefix scan)
    int kp = (int)bkeep[tid];
    unsigned* src = sA;
    unsigned* dst = sB;
    src[tid] = (unsigned)kp;
    __syncthreads();
    for (int off = 1; off < 1024; off <<= 1) {
        dst[tid] = src[tid] + ((tid >= off) ? src[tid - off] : 0u);
        __syncthreads();
        unsigned* t2 = src; src = dst; dst = t2;
    }
    int rank = (int)src[tid] - kp;
    int kcnt = (int)src[1023];

    // write output rows (scratch reads all complete; safe to overwrite)
    if (kp && rank < MAX_DET) {
        int gi = (int)bgi[tid];
        float* orow = out + ((size_t)b * MAX_DET + rank) * 89;
        orow[0] = bx0[tid]; orow[1] = by0[tid];
        orow[2] = bx1[tid]; orow[3] = by1[tid];
        orow[4] = bsc[tid];
        orow[5] = (float)bcls[tid];
        float cl = conf_logits[((size_t)b * NN + gi) * 5 + 4];
        float obj_sig = 1.0f / (1.0f + expf(-cl));
        const float4* lrow4 =
            (const float4*)(logits + ((size_t)b * NN + gi) * NCLS);
#pragma unroll 4
        for (int q = 0; q < 20; ++q) {
            float4 l4 = lrow4[q];
            orow[6 + 4 * q + 0] = obj_sig / (1.0f + expf(-l4.x));
            orow[6 + 4 * q + 1] = obj_sig / (1.0f + expf(-l4.y));
            orow[6 + 4 * q + 2] = obj_sig / (1.0f + expf(-l4.z));
            orow[6 + 4 * q + 3] = obj_sig / (1.0f + expf(-l4.w));
        }
        orow[86] = obj_sig;
        orow[87] = head[(size_t)b * NN + gi];
        orow[88] = 1.0f;
    }
    // tail zero-fill: rows [kcnt, 300) (also wipes leftover scratch bytes)
    if (tid < MAX_DET && tid >= kcnt) {
        float* orow = out + ((size_t)b * MAX_DET + tid) * 89;
#pragma unroll
        for (int q = 0; q < 89; ++q) orow[q] = 0.0f;
    }
}

extern "C" void kernel_launch(void* const* d_in, const int* in_sizes, int n_in,
                              void* d_out, int out_size, void* d_ws,
                              size_t ws_size, hipStream_t stream) {
    const float* pred        = (const float*)d_in[0];
    const float* conf_logits = (const float*)d_in[1];
    const float* logits      = (const float*)d_in[2];
    const float* head        = (const float*)d_in[3];
    float* out = (float*)d_out;

    char* ws = (char*)d_ws;
    unsigned long long* keys = (unsigned long long*)ws;  // 3,225,600 B
    unsigned* ghist = (unsigned*)(ws + (size_t)BATCH * NN * 8);  // 65,536 B

    hipMemsetAsync(ghist, 0, (size_t)BATCH * 1024 * sizeof(unsigned), stream);

    dim3 sgrid((NN + RROWS - 1) / RROWS, BATCH);
    score_kernel<<<sgrid, 512, 0, stream>>>(pred, keys, ghist, out);
    dim3 cgrid(25, BATCH);
    select_kernel<<<cgrid, 1024, 0, stream>>>(keys, ghist, out);
    nms_out_kernel<<<BATCH, 1024, 0, stream>>>(pred, conf_logits, logits,
                                               head, out);
}

// Round 16
// 354.669 us; speedup vs baseline: 1.0017x; 1.0017x over previous
//
#include <hip/hip_runtime.h>
#include <math.h>

#define BATCH 16
#define NN 25200
#define NCLS 80
#define K_PRE 1024
#define MAX_DET 300
#define CONF_T 0.4f
#define IOU_T 0.45f
#define TBIAS 0x3E000000u
// key layout (47 bits): t(25) << 22 | (NN-1-n)(15) << 7 | cls(7)
// (t, n) is unique, so cls in the low bits never affects sort order.
#define RROWS 128
#define OUT_STRIDE 26700  // floats per batch in out (300*89 = 106,800 B)
// scratch carved from each batch's own out region (output written last):
#define SCR_KEYS_OFF 0        // 2048 * 8 B bucket-grouped contender keys
#define SCR_S_OFF    16384    // 1024 * 4 B suffix-scanned hist S
#define SCR_BC_OFF   20480    // 1024 * 4 B per-bucket scatter counters
#define SCR_M_OFF    24576    // 4 B contender count M
#define SCR_X0_OFF   28672    // 1024 * 4 B each: SoA at slot = rank
#define SCR_Y0_OFF   32768
#define SCR_X1_OFF   36864
#define SCR_Y1_OFF   40960
#define SCR_AR_OFF   45056
#define SCR_SC_OFF   49152
#define SCR_CL_OFF   53248
#define SCR_GI_OFF   57344    // ends at 61440 < 106800 OK

// ---------------------------------------------------------------------------
// K1: direct-from-global score + argmax -> key + global-atomic digit hist.
// Unchanged from round 13 (verified).
// ---------------------------------------------------------------------------
__global__ void __launch_bounds__(512) score_kernel(
    const float* __restrict__ pred, unsigned long long* __restrict__ keys,
    unsigned* __restrict__ ghist, float* __restrict__ out) {
    const int tid = threadIdx.x;
    const int r = tid >> 2, sub = tid & 3;
    const int n = blockIdx.x * RROWS + r;
    const int b = blockIdx.y;

    if (blockIdx.x == 196) {  // zero gsBC for batch b (runs before K2)
        unsigned* bc = (unsigned*)((char*)(out + (size_t)b * OUT_STRIDE) +
                                   SCR_BC_OFF);
        bc[tid] = 0u;
        bc[tid + 512] = 0u;
    }

    float best = 0.0f;
    int bc_i = sub * 20;
    float obj = 0.0f;
    if (n < NN) {
        const float* row = pred + ((size_t)b * NN + n) * 85;
        obj = row[4];
        if (obj > CONF_T) {
            const float* cp = row + 5 + sub * 20;
#pragma unroll
            for (int i = 0; i < 5; ++i) {
                float4 v4 = *reinterpret_cast<const float4*>(cp + 4 * i);
                float v;
                v = v4.x * obj;
                if (v > best) { best = v; bc_i = sub * 20 + 4 * i + 0; }
                v = v4.y * obj;
                if (v > best) { best = v; bc_i = sub * 20 + 4 * i + 1; }
                v = v4.z * obj;
                if (v > best) { best = v; bc_i = sub * 20 + 4 * i + 2; }
                v = v4.w * obj;
                if (v > best) { best = v; bc_i = sub * 20 + 4 * i + 3; }
            }
        }
    }
#pragma unroll
    for (int d = 1; d < 4; d <<= 1) {
        float ov = __shfl_xor(best, d);
        int oc = __shfl_xor(bc_i, d);
        if (ov > best || (ov == best && oc < bc_i)) { best = ov; bc_i = oc; }
    }
    if (n < NN && sub == 0) {
        unsigned t = (obj > CONF_T && best > CONF_T)
                         ? (__float_as_uint(best) - TBIAS) : 0u;
        keys[(size_t)b * NN + n] =
            ((unsigned long long)t << 22) |
            ((unsigned long long)(unsigned)(NN - 1 - n) << 7) |
            (unsigned)bc_i;
        if (t) atomicAdd(&ghist[b * 1024 + (t >> 15)], 1u);
    }
}

// ---------------------------------------------------------------------------
// K2: wide select (25 blocks/batch). LDS suffix scan of ghist; scatter
// contenders bucket-grouped into out-scratch via global atomic counters.
// Block 0 persists S and M = S[dmin] (contender count).
// ---------------------------------------------------------------------------
__global__ void __launch_bounds__(1024) select_kernel(
    const unsigned long long* __restrict__ keys,
    const unsigned* __restrict__ ghist, float* __restrict__ out) {
    __shared__ unsigned sA[1024], sB[1024];
    __shared__ unsigned sel_dmin;
    const int c = blockIdx.x, b = blockIdx.y, tid = threadIdx.x;
    char* scratch = (char*)(out + (size_t)b * OUT_STRIDE);
    unsigned long long* gsk = (unsigned long long*)(scratch + SCR_KEYS_OFF);
    unsigned* gS = (unsigned*)(scratch + SCR_S_OFF);
    unsigned* gBC = (unsigned*)(scratch + SCR_BC_OFF);

    if (tid == 0) sel_dmin = 0u;
    sA[tid] = ghist[b * 1024 + tid];
    __syncthreads();
    unsigned* src = sA;
    unsigned* dst = sB;
    for (int off = 1; off < 1024; off <<= 1) {
        dst[tid] = src[tid] + ((tid + off < 1024) ? src[tid + off] : 0u);
        __syncthreads();
        unsigned* t2 = src; src = dst; dst = t2;
    }
    if (c == 0) {
        gS[tid] = src[tid];
        // dmin = smallest d with gt(d) < 1024 (unique writer: S monotone)
        unsigned base_d = (tid < 1023) ? src[tid + 1] : 0u;
        if (base_d < 1024u && (tid == 0 || src[tid] >= 1024u))
            sel_dmin = (unsigned)tid;
        __syncthreads();
        if (tid == 0)
            *(unsigned*)(scratch + SCR_M_OFF) = src[sel_dmin];
    }

    int i = c * 1024 + tid;
    if (i < NN) {
        unsigned long long key = keys[(size_t)b * NN + i];
        unsigned t = (unsigned)(key >> 22);
        if (t) {
            unsigned d = t >> 15;
            unsigned base = (d < 1023u) ? src[d + 1] : 0u;  // gt(d)
            if (base < 1024u) {
                unsigned pos = base + atomicAdd(&gBC[d], 1u);
                if (pos < 2048u) gsk[pos] = key;
            }
        }
    }
}

// ---------------------------------------------------------------------------
// K3 (prep, wide): per contender slot — exact rank via bucket-segment scan
// (L2-hot), box gather from pred, SoA write at slot = rank. 2x16 blocks of
// 1024: all loads independent -> latency pipelined. Slots >= M (and < 1024)
// get cls=255 defaults (covers [T,1024) when T < 1024).
// ---------------------------------------------------------------------------
__global__ void __launch_bounds__(1024) prep_kernel(
    const float* __restrict__ pred, float* __restrict__ out) {
    const int b = blockIdx.y;
    const int i = blockIdx.x * 1024 + threadIdx.x;  // [0, 2048)
    char* scratch = (char*)(out + (size_t)b * OUT_STRIDE);
    const unsigned long long* gsk =
        (const unsigned long long*)(scratch + SCR_KEYS_OFF);
    const unsigned* gS = (const unsigned*)(scratch + SCR_S_OFF);
    const unsigned M = *(const unsigned*)(scratch + SCR_M_OFF);
    const unsigned Mc = M < 2048u ? M : 2048u;

    if ((unsigned)i >= Mc) {
        if (i < 1024) {
            ((int*)(scratch + SCR_CL_OFF))[i] = 255;
            ((float*)(scratch + SCR_SC_OFF))[i] = 0.0f;
        }
        return;
    }
    unsigned long long key = gsk[i];
    unsigned t = (unsigned)(key >> 22);
    unsigned d = t >> 15;
    unsigned seg = (d < 1023u) ? gS[d + 1] : 0u;
    unsigned end = gS[d];
    if (end > 2048u) end = 2048u;
    unsigned r = seg;
    for (unsigned j = seg; j < end; ++j)
        if (gsk[j] > key) ++r;
    if (r < 1024u) {
        int n = NN - 1 - (int)((key >> 7) & 32767u);
        const float* row = pred + ((size_t)b * NN + n) * 85;
        float x = row[0], y = row[1], w = row[2], h = row[3];
        float vx0 = x - w * 0.5f, vy0 = y - h * 0.5f;
        float vx1 = x + w * 0.5f, vy1 = y + h * 0.5f;
        ((float*)(scratch + SCR_X0_OFF))[r] = vx0;
        ((float*)(scratch + SCR_Y0_OFF))[r] = vy0;
        ((float*)(scratch + SCR_X1_OFF))[r] = vx1;
        ((float*)(scratch + SCR_Y1_OFF))[r] = vy1;
        ((float*)(scratch + SCR_AR_OFF))[r] = (vx1 - vx0) * (vy1 - vy0);
        ((float*)(scratch + SCR_SC_OFF))[r] = __uint_as_float(t + TBIAS);
        ((int*)(scratch + SCR_CL_OFF))[r] = (int)(key & 127u);
        ((int*)(scratch + SCR_GI_OFF))[r] = n;
    }
}

// ---------------------------------------------------------------------------
// K4: per batch — load SoA -> LDS, NMS with ballot first-finder (lane owns
// 16 CONTIGUOUS slots; min alive slot = first alive lane's first alive bit:
// identical greedy order), rank scan, output + tail zero. All scratch reads
// complete before the first barrier; output writes come after.
// ---------------------------------------------------------------------------
__global__ void __launch_bounds__(1024) nms_out_kernel(
    const float* __restrict__ conf_logits, const float* __restrict__ logits,
    const float* __restrict__ head, float* __restrict__ out) {
    __shared__ unsigned sA[1024], sB[1024];
    __shared__ float bx0[K_PRE], by0[K_PRE], bx1[K_PRE], by1[K_PRE],
        bar_[K_PRE];
    __shared__ unsigned char bcls[K_PRE];
    __shared__ unsigned char bkeep[K_PRE];

    const int b = blockIdx.x, tid = threadIdx.x;
    char* scratch = (char*)(out + (size_t)b * OUT_STRIDE);

    bx0[tid] = ((const float*)(scratch + SCR_X0_OFF))[tid];
    by0[tid] = ((const float*)(scratch + SCR_Y0_OFF))[tid];
    bx1[tid] = ((const float*)(scratch + SCR_X1_OFF))[tid];
    by1[tid] = ((const float*)(scratch + SCR_Y1_OFF))[tid];
    bar_[tid] = ((const float*)(scratch + SCR_AR_OFF))[tid];
    int mycls = ((const int*)(scratch + SCR_CL_OFF))[tid];
    float mysc = ((const float*)(scratch + SCR_SC_OFF))[tid];
    int mygi = ((const int*)(scratch + SCR_GI_OFF))[tid];
    bcls[tid] = (unsigned char)mycls;
    bkeep[tid] = 0;
    __syncthreads();

    // NMS: wave wv handles classes {wv, wv+16, ..., wv+64}. Lane owns slots
    // [lane*16, lane*16+16). Ballot finds min alive slot each iteration.
    {
        const int lane = tid & 63;
        const int wv = tid >> 6;
        unsigned char myc[16];
#pragma unroll
        for (int k = 0; k < 16; ++k) myc[k] = bcls[(lane << 4) | k];

        for (int ci = 0; ci < 5; ++ci) {
            const int c = wv + (ci << 4);
            unsigned alive = 0u;
#pragma unroll
            for (int k = 0; k < 16; ++k)
                if (myc[k] == (unsigned char)c) alive |= (1u << k);
            unsigned keptm = 0u;
            for (;;) {
                unsigned long long bal = __ballot(alive != 0u);
                if (!bal) break;
                int ls = (int)__builtin_ctzll(bal);
                int cand = alive ? ((lane << 4) | __builtin_ctz(alive)) : 0;
                int s = __shfl(cand, ls);
                if (lane == ls) {
                    int kk = __builtin_ctz(alive);
                    alive &= ~(1u << kk);
                    keptm |= (1u << kk);
                }
                float ax0 = bx0[s], ay0 = by0[s], ax1 = bx1[s], ay1 = by1[s];
                float aa = bar_[s];
                unsigned rem = alive;
                while (rem) {
                    int k = __builtin_ctz(rem);
                    rem &= rem - 1;
                    int j = (lane << 4) | k;  // all alive slots are > s
                    float lx = fmaxf(ax0, bx0[j]);
                    float ly = fmaxf(ay0, by0[j]);
                    float rx = fminf(ax1, bx1[j]);
                    float ry = fminf(ay1, by1[j]);
                    float iw = fmaxf(rx - lx, 0.0f);
                    float ih = fmaxf(ry - ly, 0.0f);
                    float inter = iw * ih;
                    float iou = inter / (aa + bar_[j] - inter + 1e-7f);
                    if (iou > IOU_T) alive &= ~(1u << k);
                }
            }
            while (keptm) {
                int k = __builtin_ctz(keptm);
                keptm &= keptm - 1;
                bkeep[(lane << 4) | k] = 1;
            }
        }
    }
    __syncthreads();

    // rank kept rows (inclusive prefix scan)
    int kp = (int)bkeep[tid];
    unsigned* src = sA;
    unsigned* dst = sB;
    src[tid] = (unsigned)kp;
    __syncthreads();
    for (int off = 1; off < 1024; off <<= 1) {
        dst[tid] = src[tid] + ((tid >= off) ? src[tid - off] : 0u);
        __syncthreads();
        unsigned* t2 = src; src = dst; dst = t2;
    }
    int rank = (int)src[tid] - kp;
    int kcnt = (int)src[1023];

    // write output rows (all scratch reads completed before first barrier)
    if (kp && rank < MAX_DET) {
        float* orow = out + ((size_t)b * MAX_DET + rank) * 89;
        orow[0] = bx0[tid]; orow[1] = by0[tid];
        orow[2] = bx1[tid]; orow[3] = by1[tid];
        orow[4] = mysc;
        orow[5] = (float)mycls;
        float cl = conf_logits[((size_t)b * NN + mygi) * 5 + 4];
        float obj_sig = 1.0f / (1.0f + expf(-cl));
        const float4* lrow4 =
            (const float4*)(logits + ((size_t)b * NN + mygi) * NCLS);
#pragma unroll 4
        for (int q = 0; q < 20; ++q) {
            float4 l4 = lrow4[q];
            orow[6 + 4 * q + 0] = obj_sig / (1.0f + expf(-l4.x));
            orow[6 + 4 * q + 1] = obj_sig / (1.0f + expf(-l4.y));
            orow[6 + 4 * q + 2] = obj_sig / (1.0f + expf(-l4.z));
            orow[6 + 4 * q + 3] = obj_sig / (1.0f + expf(-l4.w));
        }
        orow[86] = obj_sig;
        orow[87] = head[(size_t)b * NN + mygi];
        orow[88] = 1.0f;
    }
    // tail zero-fill: rows [kcnt, 300) (also wipes leftover scratch bytes)
    if (tid < MAX_DET && tid >= kcnt) {
        float* orow = out + ((size_t)b * MAX_DET + tid) * 89;
#pragma unroll
        for (int q = 0; q < 89; ++q) orow[q] = 0.0f;
    }
}

extern "C" void kernel_launch(void* const* d_in, const int* in_sizes, int n_in,
                              void* d_out, int out_size, void* d_ws,
                              size_t ws_size, hipStream_t stream) {
    const float* pred        = (const float*)d_in[0];
    const float* conf_logits = (const float*)d_in[1];
    const float* logits      = (const float*)d_in[2];
    const float* head        = (const float*)d_in[3];
    float* out = (float*)d_out;

    char* ws = (char*)d_ws;
    unsigned long long* keys = (unsigned long long*)ws;  // 3,225,600 B
    unsigned* ghist = (unsigned*)(ws + (size_t)BATCH * NN * 8);  // 65,536 B

    hipMemsetAsync(ghist, 0, (size_t)BATCH * 1024 * sizeof(unsigned), stream);

    dim3 sgrid((NN + RROWS - 1) / RROWS, BATCH);
    score_kernel<<<sgrid, 512, 0, stream>>>(pred, keys, ghist, out);
    dim3 cgrid(25, BATCH);
    select_kernel<<<cgrid, 1024, 0, stream>>>(keys, ghist, out);
    dim3 pgrid(2, BATCH);
    prep_kernel<<<pgrid, 1024, 0, stream>>>(pred, out);
    nms_out_kernel<<<BATCH, 1024, 0, stream>>>(conf_logits, logits, head,
                                               out);
}